// Round 8
// baseline (103.588 us; speedup 1.0000x reference)
//
#include <hip/hip_runtime.h>
#include <math.h>

#define KC 3
#define S 12
#define SS 1728
#define AB 32
#define TLEN 64
#define NTHREADS 448
#define NWAVES 7
#define NSLICE 432
#define LN2F 0.69314718055994530942f

// load 12 foreign values with literal stride (encourages ds_read2 merging)
#define FLOAD12(pfx, P, STR) \
    pfx##0  = (P)[0*(STR)];  pfx##1  = (P)[1*(STR)];  pfx##2  = (P)[2*(STR)]; \
    pfx##3  = (P)[3*(STR)];  pfx##4  = (P)[4*(STR)];  pfx##5  = (P)[5*(STR)]; \
    pfx##6  = (P)[6*(STR)];  pfx##7  = (P)[7*(STR)];  pfx##8  = (P)[8*(STR)]; \
    pfx##9  = (P)[9*(STR)];  pfx##10 = (P)[10*(STR)]; pfx##11 = (P)[11*(STR)];

#define FMA_ROW(i, bb) { \
    float4 t0 = Tp4[3*(i)+0], t1 = Tp4[3*(i)+1], t2 = Tp4[3*(i)+2]; \
    a0.x = __builtin_fmaf((bb), t0.x, a0.x); a0.y = __builtin_fmaf((bb), t0.y, a0.y); \
    a0.z = __builtin_fmaf((bb), t0.z, a0.z); a0.w = __builtin_fmaf((bb), t0.w, a0.w); \
    a1.x = __builtin_fmaf((bb), t1.x, a1.x); a1.y = __builtin_fmaf((bb), t1.y, a1.y); \
    a1.z = __builtin_fmaf((bb), t1.z, a1.z); a1.w = __builtin_fmaf((bb), t1.w, a1.w); \
    a2.x = __builtin_fmaf((bb), t2.x, a2.x); a2.y = __builtin_fmaf((bb), t2.y, a2.y); \
    a2.z = __builtin_fmaf((bb), t2.z, a2.z); a2.w = __builtin_fmaf((bb), t2.w, a2.w); }

// One scan step. USE_INVR/IS_B are literal 0/1 (dead code elided).
#define DO_STEP(tcur, fAp, fBp, wpp, USE_INVR, IS_B) { \
    const int y_ = ys_s[(tcur)]; \
    if (active) { \
        const float4* ep_ = reinterpret_cast<const float4*>(ecp + y_*S); \
        float4 e0_ = ep_[0], e1_ = ep_[1], e2_ = ep_[2]; \
        float fa0,fa1,fa2,fa3,fa4,fa5,fa6,fa7,fa8,fa9,fa10,fa11; \
        float fb0,fb1,fb2,fb3,fb4,fb5,fb6,fb7,fb8,fb9,fb10,fb11; \
        if (sk == 0)      { FLOAD12(fa, (fAp), 144) FLOAD12(fb, (fBp), 144) } \
        else if (sk == 1) { FLOAD12(fa, (fAp), 144) FLOAD12(fb, (fBp), 12)  } \
        else              { FLOAD12(fa, (fAp), 12)  FLOAD12(fb, (fBp), 12)  } \
        float b0  = ow0.x + fa0  + fb0;  float b1  = ow0.y + fa1  + fb1; \
        float b2  = ow0.z + fa2  + fb2;  float b3  = ow0.w + fa3  + fb3; \
        float b4  = ow1.x + fa4  + fb4;  float b5  = ow1.y + fa5  + fb5; \
        float b6  = ow1.z + fa6  + fb6;  float b7  = ow1.w + fa7  + fb7; \
        float b8  = ow2.x + fa8  + fb8;  float b9  = ow2.y + fa9  + fb9; \
        float b10 = ow2.z + fa10 + fb10; float b11 = ow2.w + fa11 + fb11; \
        if (USE_INVR) { \
            b0*=invR; b1*=invR; b2*=invR; b3*=invR; b4*=invR; b5*=invR; \
            b6*=invR; b7*=invR; b8*=invR; b9*=invR; b10*=invR; b11*=invR; \
        } \
        float4 a0 = {0.f,0.f,0.f,0.f}, a1 = {0.f,0.f,0.f,0.f}, a2 = {0.f,0.f,0.f,0.f}; \
        FMA_ROW(0,b0)  FMA_ROW(1,b1)  FMA_ROW(2,b2)  FMA_ROW(3,b3) \
        FMA_ROW(4,b4)  FMA_ROW(5,b5)  FMA_ROW(6,b6)  FMA_ROW(7,b7) \
        FMA_ROW(8,b8)  FMA_ROW(9,b9)  FMA_ROW(10,b10) FMA_ROW(11,b11) \
        ow0.x = a0.x*e0_.x; ow0.y = a0.y*e0_.y; ow0.z = a0.z*e0_.z; ow0.w = a0.w*e0_.w; \
        ow1.x = a1.x*e1_.x; ow1.y = a1.y*e1_.y; ow1.z = a1.z*e1_.z; ow1.w = a1.w*e1_.w; \
        ow2.x = a2.x*e2_.x; ow2.y = a2.y*e2_.y; ow2.z = a2.z*e2_.z; ow2.w = a2.w*e2_.w; \
        float4* pw_ = reinterpret_cast<float4*>(wpp); \
        pw_[0] = ow0; pw_[1] = ow1; pw_[2] = ow2; \
    } \
    if (IS_B) { \
        if ((tt & 7) == 6) { \
            float part_ = 0.f; \
            if (active) { \
                part_ = (ow0.x+ow0.y+ow0.z+ow0.w) + (ow1.x+ow1.y+ow1.z+ow1.w) \
                      + (ow2.x+ow2.y+ow2.z+ow2.w); \
            } \
            part_ += __shfl_xor(part_, 32); part_ += __shfl_xor(part_, 16); \
            part_ += __shfl_xor(part_, 8);  part_ += __shfl_xor(part_, 4); \
            part_ += __shfl_xor(part_, 2);  part_ += __shfl_xor(part_, 1); \
            if ((tid & 63) == 0) wsum[tid >> 6] = part_; \
        } \
    } \
    __syncthreads(); \
    if (IS_B) { \
        if ((tt & 7) == 6) { \
            float R_ = wsum[0]+wsum[1]+wsum[2]+wsum[3]+wsum[4]+wsum[5]+wsum[6]; \
            if (tt != TLEN-2) { invR = __builtin_amdgcn_rcpf(R_); logR += __log2f(R_); } \
            else invR = 1.f; \
        } else invR = 1.f; \
    } }

__global__ __launch_bounds__(NTHREADS, 2)
void hmm_fwd_kernel(const int* __restrict__ ys,
                    const float* __restrict__ transition,  // [3][12][12]
                    const float* __restrict__ emission,    // [3][12][32]
                    const float* __restrict__ choice,      // [3]
                    const float* __restrict__ prior,       // [3][12]
                    float* __restrict__ out)
{
    // Ping-pong planes, each in its OWNER chain's ordering, rows of 12 (48B):
    //   P0[12*(12*s1+s2)+s0], P1[12*(12*s0+s2)+s1], P2[12*(12*s0+s1)+s2]
    __shared__ __align__(16) float PL[2][KC][SS];
    __shared__ __align__(16) float T_s[KC][S][S];
    __shared__ __align__(16) float ECt[KC][AB][S];  // [k][y][j]
    __shared__ float p_lin[KC][S];
    __shared__ float c_lin[KC];
    __shared__ int   ys_s[TLEN];
    __shared__ float wsum[NWAVES];

    const int tid = threadIdx.x;

    // ---------------- setup: linear-space tables ----------------
    if (tid < TLEN) ys_s[tid] = ys[tid];

    if (tid == 0) {
        float m = fmaxf(fmaxf(choice[0], choice[1]), choice[2]);
        float e0 = __expf(choice[0]-m), e1 = __expf(choice[1]-m), e2 = __expf(choice[2]-m);
        float inv = 1.f / (e0+e1+e2);
        c_lin[0] = e0*inv; c_lin[1] = e1*inv; c_lin[2] = e2*inv;
    }
    if (tid >= 1 && tid < 1 + KC) {
        int k = tid - 1;
        float m = -INFINITY;
        #pragma unroll
        for (int i = 0; i < S; ++i) m = fmaxf(m, prior[k*S + i]);
        float ev[S]; float s = 0.f;
        #pragma unroll
        for (int i = 0; i < S; ++i) { ev[i] = __expf(prior[k*S + i] - m); s += ev[i]; }
        float inv = 1.f / s;
        #pragma unroll
        for (int i = 0; i < S; ++i) p_lin[k][i] = ev[i] * inv;
    }
    if (tid >= 64 && tid < 64 + KC*S) {
        int r = tid - 64;
        int k = r / S, i = r % S;
        const float* row = transition + (k*S + i)*S;
        float m = -INFINITY;
        #pragma unroll
        for (int j = 0; j < S; ++j) m = fmaxf(m, row[j]);
        float ev[S]; float s = 0.f;
        #pragma unroll
        for (int j = 0; j < S; ++j) { ev[j] = __expf(row[j] - m); s += ev[j]; }
        float inv = 1.f / s;
        #pragma unroll
        for (int j = 0; j < S; ++j) T_s[k][i][j] = ev[j] * inv;
    }
    if (tid >= 128 && tid < 128 + KC*S) {    // emission -> ECt[k][y][j] = C[k]*softmax
        int r = tid - 128;
        int k = r / S, sj = r % S;
        float cm = fmaxf(fmaxf(choice[0], choice[1]), choice[2]);
        float ce = __expf(choice[k]-cm) /
                   (__expf(choice[0]-cm) + __expf(choice[1]-cm) + __expf(choice[2]-cm));
        const float* row = emission + (k*S + sj)*AB;
        float m = -INFINITY;
        #pragma unroll
        for (int a = 0; a < AB; ++a) m = fmaxf(m, row[a]);
        float ev[AB]; float s = 0.f;
        #pragma unroll
        for (int a = 0; a < AB; ++a) { ev[a] = __expf(row[a] - m); s += ev[a]; }
        float inv = ce / s;
        #pragma unroll
        for (int a = 0; a < AB; ++a) ECt[k][a][sj] = ev[a] * inv;
    }
    __syncthreads();

    // ---------------- per-thread statics ----------------
    const bool active = tid < NSLICE;
    const int ct = active ? tid : (NSLICE - 1);   // clamped for safe pointer math
    const int sk = ct / 144;                      // chain
    const int q  = ct % 144;
    const int qh = q / 12, ql = q % 12;

    int offA, offB;                               // j=0 word offsets in foreign planes
    if (sk == 0)      { offA = 12*ql + qh;   offB = 12*qh + ql;   } // P1(s144), P2(s144)
    else if (sk == 1) { offA = 12*ql + qh;   offB = 144*qh + ql;  } // P0(s144), P2(s12)
    else              { offA = 144*ql + qh;  offB = 144*qh + ql;  } // P0(s12),  P1(s12)

    const int fApl = (sk == 0) ? 1 : 0;
    const int fBpl = (sk == 2) ? 1 : 2;

    const float4* Tp4 = reinterpret_cast<const float4*>(&T_s[sk][0][0]);
    const float*  ecp = &ECt[sk][0][0];

    const float* fA0p = &PL[0][fApl][offA];
    const float* fB0p = &PL[0][fBpl][offB];
    float*       wp0  = &PL[0][sk][12*q];
    const float* fA1p = &PL[1][fApl][offA];
    const float* fB1p = &PL[1][fBpl][offB];
    float*       wp1  = &PL[1][sk][12*q];

    // init plane 0 + own registers
    float4 ow0 = {0,0,0,0}, ow1 = {0,0,0,0}, ow2 = {0,0,0,0};
    if (active) {
        float pq = (sk == 0) ? p_lin[1][qh] * p_lin[2][ql]
                 : (sk == 1) ? p_lin[0][qh] * p_lin[2][ql]
                 :             p_lin[0][qh] * p_lin[1][ql];
        float ck = c_lin[sk] * pq;
        ow0.x = p_lin[sk][0]*ck;  ow0.y = p_lin[sk][1]*ck;
        ow0.z = p_lin[sk][2]*ck;  ow0.w = p_lin[sk][3]*ck;
        ow1.x = p_lin[sk][4]*ck;  ow1.y = p_lin[sk][5]*ck;
        ow1.z = p_lin[sk][6]*ck;  ow1.w = p_lin[sk][7]*ck;
        ow2.x = p_lin[sk][8]*ck;  ow2.y = p_lin[sk][9]*ck;
        ow2.z = p_lin[sk][10]*ck; ow2.w = p_lin[sk][11]*ck;
        float4* pw = reinterpret_cast<float4*>(wp0);
        pw[0] = ow0; pw[1] = ow1; pw[2] = ow2;
    }
    __syncthreads();

    float logR = 0.f, invR = 1.f;

    #pragma unroll 1
    for (int tt = 0; tt < TLEN; tt += 2) {
        DO_STEP(tt,     fA0p, fB0p, wp1, 1, 0)   // read plane0, write plane1
        DO_STEP(tt + 1, fA1p, fB1p, wp0, 0, 1)   // read plane1, write plane0
    }

    // final: total mass at t=63 is in wsum (its normalizer never applied)
    if (tid == 0) {
        float R = wsum[0]+wsum[1]+wsum[2]+wsum[3]+wsum[4]+wsum[5]+wsum[6];
        out[0] = LN2F * (__log2f(R) + logR);
    }
}

extern "C" void kernel_launch(void* const* d_in, const int* in_sizes, int n_in,
                              void* d_out, int out_size, void* d_ws, size_t ws_size,
                              hipStream_t stream) {
    const int*   ys         = (const int*)  d_in[0];
    const float* transition = (const float*)d_in[1];
    const float* emission   = (const float*)d_in[2];
    const float* choice     = (const float*)d_in[3];
    const float* prior      = (const float*)d_in[4];
    float* out = (float*)d_out;

    hipLaunchKernelGGL(hmm_fwd_kernel, dim3(1), dim3(NTHREADS), 0, stream,
                       ys, transition, emission, choice, prior, out);
}

// Round 9
// 60.342 us; speedup vs baseline: 1.7167x; 1.7167x over previous
//
#include <hip/hip_runtime.h>
#include <math.h>

#define KC 3
#define S 12
#define SS 1728
#define AB 32
#define TLEN 64
#define NTHREADS 896
#define NWAVES 14
#define NACT 864            // 432 slices x 2 threads
#define LN2F 0.69314718055994530942f

__global__ __launch_bounds__(NTHREADS, 4)   // 4 waves/SIMD -> VGPR cap 128
void hmm_fwd_kernel(const int* __restrict__ ys,
                    const float* __restrict__ transition,  // [3][12][12]
                    const float* __restrict__ emission,    // [3][12][32]
                    const float* __restrict__ choice,      // [3]
                    const float* __restrict__ prior,       // [3][12]
                    float* __restrict__ out)
{
    // A planes in natural state order n = s0*144 + s1*12 + s2
    __shared__ __align__(16) float APL[KC][SS];
    __shared__ __align__(16) float BETA[SS];
    __shared__ __align__(16) float ECt[KC][AB][16];  // [k][y][8h+m], padded rows
    __shared__ float T_s[KC][S][S];
    __shared__ float p_lin[KC][S];
    __shared__ float c_lin[KC];
    __shared__ int   ys_s[TLEN];
    __shared__ float wsum[NWAVES];

    const int tid = threadIdx.x;

    // ---------------- setup: linear-space tables ----------------
    if (tid < TLEN) ys_s[tid] = ys[tid];

    if (tid == 0) {
        float m = fmaxf(fmaxf(choice[0], choice[1]), choice[2]);
        float e0 = __expf(choice[0]-m), e1 = __expf(choice[1]-m), e2 = __expf(choice[2]-m);
        float inv = 1.f / (e0+e1+e2);
        c_lin[0] = e0*inv; c_lin[1] = e1*inv; c_lin[2] = e2*inv;
    }
    if (tid >= 1 && tid < 1 + KC) {
        int k = tid - 1;
        float m = -INFINITY;
        #pragma unroll
        for (int i = 0; i < S; ++i) m = fmaxf(m, prior[k*S + i]);
        float ev[S]; float s = 0.f;
        #pragma unroll
        for (int i = 0; i < S; ++i) { ev[i] = __expf(prior[k*S + i] - m); s += ev[i]; }
        float inv = 1.f / s;
        #pragma unroll
        for (int i = 0; i < S; ++i) p_lin[k][i] = ev[i] * inv;
    }
    if (tid >= 64 && tid < 64 + KC*S) {
        int r = tid - 64;
        int k = r / S, i = r % S;
        const float* row = transition + (k*S + i)*S;
        float m = -INFINITY;
        #pragma unroll
        for (int j = 0; j < S; ++j) m = fmaxf(m, row[j]);
        float ev[S]; float s = 0.f;
        #pragma unroll
        for (int j = 0; j < S; ++j) { ev[j] = __expf(row[j] - m); s += ev[j]; }
        float inv = 1.f / s;
        #pragma unroll
        for (int j = 0; j < S; ++j) T_s[k][i][j] = ev[j] * inv;
    }
    if (tid >= 128 && tid < 128 + KC*S) {    // emission -> ECt[k][y][8h+m] = C[k]*softmax
        int r = tid - 128;
        int k = r / S, sj = r % S;
        float cm = fmaxf(fmaxf(choice[0], choice[1]), choice[2]);
        float ce = __expf(choice[k]-cm) /
                   (__expf(choice[0]-cm) + __expf(choice[1]-cm) + __expf(choice[2]-cm));
        const float* row = emission + (k*S + sj)*AB;
        float m = -INFINITY;
        #pragma unroll
        for (int a = 0; a < AB; ++a) m = fmaxf(m, row[a]);
        float ev[AB]; float s = 0.f;
        #pragma unroll
        for (int a = 0; a < AB; ++a) { ev[a] = __expf(row[a] - m); s += ev[a]; }
        float inv = ce / s;
        const int slot = (sj / 6) * 8 + (sj % 6);
        #pragma unroll
        for (int a = 0; a < AB; ++a) ECt[k][a][slot] = ev[a] * inv;
    }
    __syncthreads();

    // ---------------- per-thread statics ----------------
    const bool act = tid < NACT;
    const int ct = act ? tid : (NACT - 1);
    const int sl = ct >> 1;            // slice 0..431
    const int h  = ct & 1;             // output half: columns 6h..6h+5
    const int sk = sl / 144;           // chain
    const int q  = sl % 144;
    const int qh = q / 12, ql = q % 12;

    // beta gather base (natural order), per chain
    const int rdb = (sk == 0) ? q : (sk == 1) ? 144*qh + ql : 12*q;
    // A write base/stride for own chain
    const int wstr = (sk == 0) ? 144 : (sk == 1) ? 12 : 1;
    const int wbas = rdb + wstr * 6 * h;           // j = 6h + m
    float* const wap = &APL[sk][wbas];
    const float* const ecp = &ECt[sk][0][8*h];

    // T columns 6h..6h+5 in registers (72 floats; static indices only)
    float Trg[S][6];
    if (act) {
        #pragma unroll
        for (int i = 0; i < S; ++i) {
            #pragma unroll
            for (int m = 0; m < 6; ++m) Trg[i][m] = T_s[sk][i][6*h + m];
        }
    }

    // init A planes: thread p owns natural states 2p, 2p+1 (s2 even, no carry)
    if (act) {
        const int sA = 2*tid;
        const int a0 = sA/144, b0 = (sA/12)%12, c0 = sA%12;
        const float pp = p_lin[0][a0]*p_lin[1][b0];
        const float pA = pp*p_lin[2][c0], pB = pp*p_lin[2][c0+1];
        #pragma unroll
        for (int k = 0; k < KC; ++k) {
            float2 v; v.x = pA*c_lin[k]; v.y = pB*c_lin[k];
            *reinterpret_cast<float2*>(&APL[k][sA]) = v;
        }
    }
    __syncthreads();

    // ---------------- 64 steps, 2 barriers each ----------------
    float logR = 0.f, invR = 1.f;
    const int s2p = 2*tid;

    #pragma unroll 1
    for (int t = 0; t < TLEN; ++t) {
        const int y = ys_s[t];

        if (act) {
            // phase 1: beta for 2 states (b64 reads/write, conflict-free)
            float2 a0 = *reinterpret_cast<const float2*>(&APL[0][s2p]);
            float2 a1 = *reinterpret_cast<const float2*>(&APL[1][s2p]);
            float2 a2 = *reinterpret_cast<const float2*>(&APL[2][s2p]);
            float2 b;
            b.x = (a0.x + a1.x + a2.x) * invR;
            b.y = (a0.y + a1.y + a2.y) * invR;
            *reinterpret_cast<float2*>(&BETA[s2p]) = b;
        }
        __syncthreads();   // barrier A: BETA ready

        float acc0=0.f, acc1=0.f, acc2=0.f, acc3=0.f, acc4=0.f, acc5=0.f;
        if (act) {
            // E half-row (broadcast, padded to 8 words, no branch)
            float4 e03 = *reinterpret_cast<const float4*>(&ecp[y*16]);
            float2 e45 = *reinterpret_cast<const float2*>(&ecp[y*16 + 4]);

            // gather 12 betas (pair lanes broadcast the same addresses)
            float bv[S];
            if (sk == 0) {
                #pragma unroll
                for (int i = 0; i < S; ++i) bv[i] = BETA[rdb + 144*i];
            } else if (sk == 1) {
                #pragma unroll
                for (int i = 0; i < S; ++i) bv[i] = BETA[rdb + 12*i];
            } else {
                float4 r0 = *reinterpret_cast<const float4*>(&BETA[rdb + 0]);
                float4 r1 = *reinterpret_cast<const float4*>(&BETA[rdb + 4]);
                float4 r2 = *reinterpret_cast<const float4*>(&BETA[rdb + 8]);
                bv[0]=r0.x; bv[1]=r0.y; bv[2] =r0.z; bv[3] =r0.w;
                bv[4]=r1.x; bv[5]=r1.y; bv[6] =r1.z; bv[7] =r1.w;
                bv[8]=r2.x; bv[9]=r2.y; bv[10]=r2.z; bv[11]=r2.w;
            }

            #pragma unroll
            for (int i = 0; i < S; ++i) {
                const float bb = bv[i];
                acc0 = __builtin_fmaf(bb, Trg[i][0], acc0);
                acc1 = __builtin_fmaf(bb, Trg[i][1], acc1);
                acc2 = __builtin_fmaf(bb, Trg[i][2], acc2);
                acc3 = __builtin_fmaf(bb, Trg[i][3], acc3);
                acc4 = __builtin_fmaf(bb, Trg[i][4], acc4);
                acc5 = __builtin_fmaf(bb, Trg[i][5], acc5);
            }
            acc0 *= e03.x; acc1 *= e03.y; acc2 *= e03.z;
            acc3 *= e03.w; acc4 *= e45.x; acc5 *= e45.y;

            // write 6 outputs to own plane
            if (sk == 2) {
                // contiguous 6 words at wbas (16B/8B aligned for both halves)
                if (h == 0) {
                    *reinterpret_cast<float4*>(&wap[0]) = make_float4(acc0, acc1, acc2, acc3);
                    *reinterpret_cast<float2*>(&wap[4]) = make_float2(acc4, acc5);
                } else {
                    *reinterpret_cast<float2*>(&wap[0]) = make_float2(acc0, acc1);
                    *reinterpret_cast<float4*>(&wap[2]) = make_float4(acc2, acc3, acc4, acc5);
                }
            } else {
                wap[0*wstr] = acc0; wap[1*wstr] = acc1; wap[2*wstr] = acc2;
                wap[3*wstr] = acc3; wap[4*wstr] = acc4; wap[5*wstr] = acc5;
            }
        }

        if ((t & 7) == 7) {
            float part = acc0 + acc1 + acc2 + acc3 + acc4 + acc5;   // 0 for inactive
            part += __shfl_xor(part, 32); part += __shfl_xor(part, 16);
            part += __shfl_xor(part, 8);  part += __shfl_xor(part, 4);
            part += __shfl_xor(part, 2);  part += __shfl_xor(part, 1);
            if ((tid & 63) == 0) wsum[tid >> 6] = part;
        }
        __syncthreads();   // barrier B: A planes (and wsum) visible

        if ((t & 7) == 7 && t < TLEN-1) {
            float R = 0.f;
            #pragma unroll
            for (int w = 0; w < NWAVES; ++w) R += wsum[w];
            invR = __builtin_amdgcn_rcpf(R);
            logR += __log2f(R);
        } else {
            invR = 1.f;
        }
    }

    // final: total mass at t=63 is in wsum (its normalizer never applied)
    if (tid == 0) {
        float R = 0.f;
        #pragma unroll
        for (int w = 0; w < NWAVES; ++w) R += wsum[w];
        out[0] = LN2F * (__log2f(R) + logR);
    }
}

extern "C" void kernel_launch(void* const* d_in, const int* in_sizes, int n_in,
                              void* d_out, int out_size, void* d_ws, size_t ws_size,
                              hipStream_t stream) {
    const int*   ys         = (const int*)  d_in[0];
    const float* transition = (const float*)d_in[1];
    const float* emission   = (const float*)d_in[2];
    const float* choice     = (const float*)d_in[3];
    const float* prior      = (const float*)d_in[4];
    float* out = (float*)d_out;

    hipLaunchKernelGGL(hmm_fwd_kernel, dim3(1), dim3(NTHREADS), 0, stream,
                       ys, transition, emission, choice, prior, out);
}